// Round 9
// baseline (201.456 us; speedup 1.0000x reference)
//
#include <hip/hip_runtime.h>
#include <math.h>

#define L_SEQ 16384
#define H_DIM 1024
#define P_DIM 512
#define N2P   1024
#define KDIM  1024
#define NKT   16     // KDIM / 64 K-tiles
#define CHUNK 64
#define NCHUNK 256   // L_SEQ / CHUNK

typedef __attribute__((ext_vector_type(8))) short short8;
typedef __attribute__((ext_vector_type(4))) float f32x4;

__device__ __forceinline__ unsigned short f2bf(float f){
    unsigned int u = __float_as_uint(f);
    u = (u + 0x7FFFu + ((u >> 16) & 1u)) >> 16;
    return (unsigned short)u;
}
__device__ __forceinline__ float bf2f(unsigned int lo16){
    return __uint_as_float(lo16 << 16);
}

// ---------------- prep ----------------
__global__ void k_prep_lambda(const float* __restrict__ lre, const float* __restrict__ lim,
                              const float* __restrict__ lstep,
                              float* __restrict__ lam, float* __restrict__ coef,
                              float* __restrict__ lpow)
{
    int p = threadIdx.x;
    double step = exp((double)lstep[p]);
    double dr = (double)lre[p], di = (double)lim[p];
    double ar = dr*step, ai = di*step;
    double er = exp(ar);
    double lbr = er*cos(ai), lbi = er*sin(ai);
    lam[2*p] = (float)lbr; lam[2*p+1] = (float)lbi;
    double nr = lbr - 1.0, ni = lbi;
    double d2 = dr*dr + di*di;
    coef[2*p]   = (float)((nr*dr + ni*di)/d2);
    coef[2*p+1] = (float)((ni*dr - nr*di)/d2);
    double xr = lbr, xi = lbi;
    #pragma unroll
    for (int s=0;s<6;s++){ double t = xr*xr - xi*xi; xi = 2.0*xr*xi; xr = t; } // ^64
    lpow[2*p] = (float)xr; lpow[2*p+1] = (float)xi;
}

__global__ __launch_bounds__(256)
void k_prep_BB(const float* __restrict__ B, const float* __restrict__ coef,
               unsigned short* __restrict__ BB)
{
    int i = blockIdx.x*256 + threadIdx.x;   // i = p*H + h
    int p = i >> 10, h = i & 1023;
    float br = B[2*i], bi = B[2*i+1];
    float cr = coef[2*p], ci = coef[2*p+1];
    BB[(size_t)(2*p)*H_DIM + h]   = f2bf(cr*br - ci*bi);
    BB[(size_t)(2*p+1)*H_DIM + h] = f2bf(cr*bi + ci*br);
}

__global__ __launch_bounds__(256)
void k_prep_CC(const float* __restrict__ C, unsigned short* __restrict__ CC)
{
    int i = blockIdx.x*256 + threadIdx.x;   // i = h*P + p
    int h = i >> 9, p = i & 511;
    float cr = C[2*i], ci = C[2*i+1];
    CC[(size_t)h*N2P + 2*p]     = f2bf(2.f*cr);
    CC[(size_t)h*N2P + 2*p + 1] = f2bf(-2.f*ci);
}

__global__ __launch_bounds__(256)
void k_cast(const float4* __restrict__ u, unsigned short* __restrict__ o)
{
    int i = blockIdx.x*256 + threadIdx.x;
    float4 a = u[2*i], b = u[2*i+1];
    union { short8 v; unsigned short s[8]; } r;
    r.s[0]=f2bf(a.x); r.s[1]=f2bf(a.y); r.s[2]=f2bf(a.z); r.s[3]=f2bf(a.w);
    r.s[4]=f2bf(b.x); r.s[5]=f2bf(b.y); r.s[6]=f2bf(b.z); r.s[7]=f2bf(b.w);
    *reinterpret_cast<short8*>(o + (size_t)i*8) = r.v;
}

// ---------------- GEMM: 128x128 tile, 4 waves, A in LDS (dbuf), B from L2 ----------
// C[M][1024] = A[M][1024]bf16 @ Bm[1024][1024]bf16^T
// B (2 MiB total) is L2-resident per XCD -> direct global short8 loads, no LDS.
// A: 16KB/KT, 2-parity dbuf = 32KB LDS -> 3+ independent blocks/CU (desynced
// barriers give the MFMA/LDS/VMEM overlap no intra-block schedule achieved).
// Swizzle (both sides, 0 conflicts): phys 16B-chunk = logical ^ (row&7).
// Per KT: STAGE_A(kt+1 -> other parity) ; load 8 B-frags (plain derefs) ;
//         compute (compiler-scheduled) ; vmcnt(0) ; raw s_barrier.
template<int EPI>
__global__ __launch_bounds__(256, 3)
void gemm128(const unsigned short* __restrict__ A, const unsigned short* __restrict__ Bm,
             float* __restrict__ Cf, unsigned short* __restrict__ Cb,
             const float* __restrict__ Dv, const unsigned short* __restrict__ U16)
{
    __shared__ char lds[32768];
    const int tid  = threadIdx.x;
    const int lane = tid & 63;
    const int wid  = tid >> 6;
    const int wm = wid >> 1, wn = wid & 1;          // 2(M) x 2(N) waves, wave = 64x64
    const int wg = ((int)blockIdx.x & 7) * 128 + ((int)blockIdx.x >> 3);  // XCD swizzle (1024%8==0)
    const int tm = wg >> 3, tn = wg & 7;
    const int lr = lane & 15;

    // staging: thread covers rows tid>>3 (+32,+64,+96), 16B chunk tid&7; dst linear,
    // source col pre-swizzled: logical chunk = (tid&7)^(row&7).
    const int srow = tid >> 3;                               // 0..31
    const int scol = ((tid & 7) ^ ((tid >> 3) & 7)) << 3;    // ushort units
    // A-frag reads: row = wm*64 + m*16 + lr; byte = row*128 + ((g|4ks)^(lr&7))*16
    const int kc0 = (((lane >> 4)      ^ (lr & 7)) << 4);
    const int kc1 = ((((lane >> 4) | 4) ^ (lr & 7)) << 4);
    const int aOff = (wm*64 + lr)*128;                       // + m*2048 + kc

    // B-frag base: row = tn*128 + wn*64 + n*16 + lr, k-chunk (lane>>4)*8
    const unsigned short* bP = Bm + (size_t)(tn*128 + wn*64 + lr)*KDIM + ((lane >> 4) << 3);

#define GLOAD(SRC, DST) __builtin_amdgcn_global_load_lds( \
        (const __attribute__((address_space(1))) void*)(SRC), \
        (__attribute__((address_space(3))) void*)(DST), 16, 0, 0)
#define STAGE_A(kt_) do{ \
    char* d_ = lds + (((kt_)&1)<<14) + tid*16; \
    const unsigned short* s_ = A + (size_t)(tm*128 + srow)*KDIM + (size_t)(kt_)*64 + scol; \
    GLOAD(s_,                    d_); \
    GLOAD(s_ + (size_t)32*KDIM,  d_ + 4096); \
    GLOAD(s_ + (size_t)64*KDIM,  d_ + 8192); \
    GLOAD(s_ + (size_t)96*KDIM,  d_ + 12288); }while(0)
#define RD(OFF) (*(const short8*)(lds + (OFF)))
#define MFMA(a,b,c) __builtin_amdgcn_mfma_f32_16x16x32_bf16(a,b,c,0,0,0)
#define VMC0  asm volatile("s_waitcnt vmcnt(0)" ::: "memory")
#define ABAR  asm volatile("s_barrier" ::: "memory")

    f32x4 acc[4][4];
    #pragma unroll
    for (int m=0;m<4;m++)
        #pragma unroll
        for (int n=0;n<4;n++) acc[m][n] = (f32x4){0.f,0.f,0.f,0.f};

    // prologue: stage KT0 into parity 0
    STAGE_A(0);
    VMC0; ABAR;

    #pragma unroll 2
    for (int kt = 0; kt < NKT; ++kt) {
        const int sb = (kt & 1) << 14;
        const int tN = (kt+1 < NKT) ? kt+1 : NKT-1;   // tail dummy (other parity, never read)
        STAGE_A(tN);                                   // writes other parity

        const unsigned short* bK = bP + (size_t)kt*64;
        short8 b0[4], b1[4];
        #pragma unroll
        for (int n=0;n<4;n++){
            b0[n] = *reinterpret_cast<const short8*>(bK + n*16*KDIM);
            b1[n] = *reinterpret_cast<const short8*>(bK + n*16*KDIM + 32);
        }
        // ks = 0
        {
            short8 afr[4];
            #pragma unroll
            for (int m=0;m<4;m++) afr[m] = RD(sb + aOff + m*2048 + kc0);
            #pragma unroll
            for (int m=0;m<4;m++)
                #pragma unroll
                for (int n=0;n<4;n++) acc[m][n] = MFMA(afr[m], b0[n], acc[m][n]);
        }
        // ks = 1
        {
            short8 afr[4];
            #pragma unroll
            for (int m=0;m<4;m++) afr[m] = RD(sb + aOff + m*2048 + kc1);
            #pragma unroll
            for (int m=0;m<4;m++)
                #pragma unroll
                for (int n=0;n<4;n++) acc[m][n] = MFMA(afr[m], b1[n], acc[m][n]);
        }
        VMC0;   // own stage-writes (and B loads) retired; stages issued a full KT ago
        ABAR;   // all waves done reading parity kt&1; next iter may overwrite it
    }

    const int orow0 = tm*128 + wm*64 + (lane>>4)*4;
    const int ocol0 = tn*128 + wn*64 + lr;
    #pragma unroll
    for (int m=0;m<4;m++){
        #pragma unroll
        for (int n=0;n<4;n++){
            int row = orow0 + m*16, col = ocol0 + n*16;
            #pragma unroll
            for (int j=0;j<4;j++){
                size_t idx = (size_t)(row + j)*N2P + col;
                if (EPI) Cf[idx] = acc[m][n][j] + Dv[col]*bf2f(U16[idx]);
                else     Cb[idx] = f2bf(acc[m][n][j]);
            }
        }
    }
#undef GLOAD
#undef STAGE_A
#undef RD
#undef MFMA
#undef VMC0
#undef ABAR
}

// ---------------- scan phase 1: per-(chunk, p) aggregate (Bu in bf16 pairs) -------
__global__ __launch_bounds__(512)
void k_agg(const unsigned int* __restrict__ Bu, const float* __restrict__ lam,
           float* __restrict__ agg)
{
    int p = threadIdx.x, c = blockIdx.x;
    float lrr = lam[2*p], lii = lam[2*p+1];
    float xr = 0.f, xi = 0.f;
    const unsigned int* b2 = Bu + (size_t)c*CHUNK*512 + p;
    #pragma unroll 4
    for (int t=0;t<CHUNK;t++){
        unsigned int b = b2[(size_t)t*512];
        float br = __uint_as_float(b << 16);
        float bi = __uint_as_float(b & 0xffff0000u);
        float tr = lrr*xr - lii*xi + br;
        xi = lrr*xi + lii*xr + bi;
        xr = tr;
    }
    agg[((size_t)c*P_DIM + p)*2]     = xr;
    agg[((size_t)c*P_DIM + p)*2 + 1] = xi;
}

// ---------------- scan phase 2: Kogge-Stone over chunks ---------------------
__global__ __launch_bounds__(256)
void k_scan(const float* __restrict__ agg, const float* __restrict__ lpow,
            float* __restrict__ xinit)
{
    __shared__ float sr[NCHUNK], si[NCHUNK];
    int c = threadIdx.x, p = blockIdx.x;
    float xr = agg[((size_t)c*P_DIM + p)*2];
    float xi = agg[((size_t)c*P_DIM + p)*2 + 1];
    sr[c] = xr; si[c] = xi;
    float wr = lpow[2*p], wi = lpow[2*p+1];
    for (int s=1; s<NCHUNK; s<<=1){
        __syncthreads();
        float ur = 0.f, ui = 0.f;
        if (c >= s){ ur = sr[c-s]; ui = si[c-s]; }
        __syncthreads();
        xr += wr*ur - wi*ui;
        xi += wr*ui + wi*ur;
        sr[c] = xr; si[c] = xi;
        float t = wr*wr - wi*wi; wi = 2.f*wr*wi; wr = t;
    }
    __syncthreads();
    float er = 0.f, ei = 0.f;
    if (c > 0){ er = sr[c-1]; ei = si[c-1]; }
    xinit[((size_t)c*P_DIM + p)*2]     = er;
    xinit[((size_t)c*P_DIM + p)*2 + 1] = ei;
}

// ---------------- scan phase 3: apply + emit bf16 pairs ----------------------
__global__ __launch_bounds__(512)
void k_apply(const unsigned int* __restrict__ Bu, const float* __restrict__ lam,
             const float* __restrict__ xinit, unsigned int* __restrict__ xs)
{
    int p = threadIdx.x, c = blockIdx.x;
    float lrr = lam[2*p], lii = lam[2*p+1];
    float xr = xinit[((size_t)c*P_DIM + p)*2];
    float xi = xinit[((size_t)c*P_DIM + p)*2 + 1];
    const unsigned int* b2 = Bu + (size_t)c*CHUNK*512 + p;
    unsigned int* o = xs + (size_t)c*CHUNK*512 + p;
    #pragma unroll 4
    for (int t=0;t<CHUNK;t++){
        unsigned int b = b2[(size_t)t*512];
        float br = __uint_as_float(b << 16);
        float bi = __uint_as_float(b & 0xffff0000u);
        float tr = lrr*xr - lii*xi + br;
        xi = lrr*xi + lii*xr + bi;
        xr = tr;
        o[(size_t)t*512] = (unsigned int)f2bf(xr) | ((unsigned int)f2bf(xi) << 16);
    }
}

extern "C" void kernel_launch(void* const* d_in, const int* in_sizes, int n_in,
                              void* d_out, int out_size, void* d_ws, size_t ws_size,
                              hipStream_t stream)
{
    const float* u   = (const float*)d_in[0];
    const float* lre = (const float*)d_in[1];
    const float* lim = (const float*)d_in[2];
    const float* B   = (const float*)d_in[3];
    const float* C   = (const float*)d_in[4];
    const float* D   = (const float*)d_in[5];
    const float* ls  = (const float*)d_in[6];
    float* out = (float*)d_out;

    char* w = (char*)d_ws;
    unsigned short* u16  = (unsigned short*)(w + 0);          // 32 MiB
    unsigned short* xs16 = (unsigned short*)(w + 33554432);   // 32 MiB
    unsigned short* Bu16 = (unsigned short*)(w + 67108864);   // 32 MiB
    unsigned short* BB   = (unsigned short*)(w + 100663296);  // 2 MiB
    unsigned short* CC   = (unsigned short*)(w + 102760448);  // 2 MiB
    float* lam   = (float*)(w + 104857600);
    float* coef  = (float*)(w + 104861696);
    float* lpow  = (float*)(w + 104865792);
    float* agg   = (float*)(w + 104869888);                   // 1 MiB
    float* xinit = (float*)(w + 105918464);                   // 1 MiB

    k_prep_lambda<<<1, P_DIM, 0, stream>>>(lre, lim, ls, lam, coef, lpow);
    k_prep_BB<<<(P_DIM*H_DIM)/256, 256, 0, stream>>>(B, coef, BB);
    k_prep_CC<<<(H_DIM*P_DIM)/256, 256, 0, stream>>>(C, CC);
    k_cast<<<(L_SEQ*H_DIM)/(256*8), 256, 0, stream>>>((const float4*)u, u16);

    gemm128<0><<<1024, 256, 0, stream>>>(u16, BB, nullptr, Bu16, nullptr, nullptr);

    k_agg<<<NCHUNK, P_DIM, 0, stream>>>((const unsigned int*)Bu16, lam, agg);
    k_scan<<<P_DIM, NCHUNK, 0, stream>>>(agg, lpow, xinit);
    k_apply<<<NCHUNK, P_DIM, 0, stream>>>((const unsigned int*)Bu16, lam, xinit,
                                          (unsigned int*)xs16);

    gemm128<1><<<1024, 256, 0, stream>>>(xs16, CC, out, nullptr, D, u16);
}

// Round 10
// 149.899 us; speedup vs baseline: 1.3439x; 1.3439x over previous
//
#include <hip/hip_runtime.h>
#include <math.h>

#define L_SEQ 16384
#define H_DIM 1024
#define P_DIM 512
#define N2P   1024
#define KDIM  1024
#define NKT2  32     // KDIM / 32 K-tiles
#define CHUNK 64
#define NCHUNK 256   // L_SEQ / CHUNK

typedef __attribute__((ext_vector_type(8))) short short8;
typedef __attribute__((ext_vector_type(4))) float f32x4;

__device__ __forceinline__ unsigned short f2bf(float f){
    unsigned int u = __float_as_uint(f);
    u = (u + 0x7FFFu + ((u >> 16) & 1u)) >> 16;
    return (unsigned short)u;
}
__device__ __forceinline__ float bf2f(unsigned int lo16){
    return __uint_as_float(lo16 << 16);
}

// ---------------- prep: lambda_bar powers (double precision, scan-critical) -------
__global__ void k_prep_lambda(const float* __restrict__ lre, const float* __restrict__ lim,
                              const float* __restrict__ lstep,
                              float* __restrict__ lam, float* __restrict__ coef,
                              float* __restrict__ lpow)
{
    int p = threadIdx.x;
    double step = exp((double)lstep[p]);
    double dr = (double)lre[p], di = (double)lim[p];
    double ar = dr*step, ai = di*step;
    double er = exp(ar);
    double lbr = er*cos(ai), lbi = er*sin(ai);
    lam[2*p] = (float)lbr; lam[2*p+1] = (float)lbi;
    double nr = lbr - 1.0, ni = lbi;
    double d2 = dr*dr + di*di;
    coef[2*p]   = (float)((nr*dr + ni*di)/d2);
    coef[2*p+1] = (float)((ni*dr - nr*di)/d2);
    double xr = lbr, xi = lbi;
    #pragma unroll
    for (int s=0;s<6;s++){ double t = xr*xr - xi*xi; xi = 2.0*xr*xi; xr = t; } // ^64
    lpow[2*p] = (float)xr; lpow[2*p+1] = (float)xi;
}

// merged BB + CC prep (saves a launch): bid<2048 -> BB, else CC
__global__ __launch_bounds__(256)
void k_prep_bc(const float* __restrict__ B, const float* __restrict__ C,
               const float* __restrict__ coef,
               unsigned short* __restrict__ BB, unsigned short* __restrict__ CC)
{
    int bid = blockIdx.x;
    if (bid < 2048){
        int i = bid*256 + threadIdx.x;   // i = p*H + h
        int p = i >> 10, h = i & 1023;
        float br = B[2*i], bi = B[2*i+1];
        float cr = coef[2*p], ci = coef[2*p+1];
        BB[(size_t)(2*p)*H_DIM + h]   = f2bf(cr*br - ci*bi);
        BB[(size_t)(2*p+1)*H_DIM + h] = f2bf(cr*bi + ci*br);
    } else {
        int i = (bid-2048)*256 + threadIdx.x;   // i = h*P + p
        int h = i >> 9, p = i & 511;
        float cr = C[2*i], ci = C[2*i+1];
        CC[(size_t)h*N2P + 2*p]     = f2bf(2.f*cr);
        CC[(size_t)h*N2P + 2*p + 1] = f2bf(-2.f*ci);
    }
}

__global__ __launch_bounds__(256)
void k_cast(const float4* __restrict__ u, unsigned short* __restrict__ o)
{
    int i = blockIdx.x*256 + threadIdx.x;
    float4 a = u[2*i], b = u[2*i+1];
    union { short8 v; unsigned short s[8]; } r;
    r.s[0]=f2bf(a.x); r.s[1]=f2bf(a.y); r.s[2]=f2bf(a.z); r.s[3]=f2bf(a.w);
    r.s[4]=f2bf(b.x); r.s[5]=f2bf(b.y); r.s[6]=f2bf(b.z); r.s[7]=f2bf(b.w);
    *reinterpret_cast<short8*>(o + (size_t)i*8) = r.v;
}

// ---------------- GEMM: 128x256 tile, BK=32, 4 waves (64x128 each), 2 blocks/CU ----
// C[M][1024] = A[M][1024]bf16 @ Bm[1024][1024]bf16^T
// Both operands LDS-staged (R9 lesson: B-from-global puts L2 latency on the
// critical path). 3 slots x 24KB (A 8KB + B 16KB) = 72KB -> 2 independent
// blocks/CU (the structural lever: desynced barriers overlap LDS port & MFMA).
// acc[4][8]=128 VGPR -> 2 waves/SIMD. Depth-2 prefetch, uniform vmcnt(12)/KT
// (retires tile kt, keeps kt+1,kt+2 in flight; loads land ~2 KT early).
// Swizzle (64B rows, 0 conflicts measured R4): phys 16B-chunk = logical ^ ((row>>1)&3),
// both sides (pre-swizzled global source + swizzled read).
template<int EPI>
__global__ __launch_bounds__(256, 2)
void gemm128n(const unsigned short* __restrict__ A, const unsigned short* __restrict__ Bm,
              float* __restrict__ Cf, unsigned short* __restrict__ Cb,
              const float* __restrict__ Dv, const unsigned short* __restrict__ U16)
{
    __shared__ char lds[73728];                       // 3 x 24576
    const int tid  = threadIdx.x;
    const int lane = tid & 63;
    const int wid  = tid >> 6;
    const int wm = wid >> 1, wn = wid & 1;            // 2(M) x 2(N), wave = 64x128
    const int wg = ((int)blockIdx.x & 7) * 64 + ((int)blockIdx.x >> 3);  // XCD swizzle (512%8==0)
    const int tm = wg >> 2, tn = wg & 3;
    const int lr = lane & 15;

    // staging: thread covers row tid>>2 (0..63), 16B chunk tid&3; dst linear tid*16;
    // source col pre-swizzled: logical chunk = (tid&3) ^ ((row>>1)&3)
    const int scol = (((tid & 3) ^ ((tid >> 3) & 3)) << 3);   // ushort units
    const int srow = tid >> 2;                                 // 0..63
    // reads: row-major [rows][64B]; byte = row*64 + ((lane>>4)^((lr>>1)&3))*16
    const int kc   = (((lane >> 4) ^ ((lr >> 1) & 3)) << 4);
    const int aOff = (wm*64  + lr)*64 + kc;                    // + m*1024
    const int bOff = 8192 + (wn*128 + lr)*64 + kc;             // + n*1024

#define GLOAD(SRC, DST) __builtin_amdgcn_global_load_lds( \
        (const __attribute__((address_space(1))) void*)(SRC), \
        (__attribute__((address_space(3))) void*)(DST), 16, 0, 0)
#define STAGE(kt_, slot_) do{ \
    char* d_ = lds + (slot_)*24576 + tid*16; \
    const unsigned short* sa = A + (size_t)(tm*128 + srow)*KDIM + (size_t)(kt_)*32 + scol; \
    GLOAD(sa,                    d_); \
    GLOAD(sa + (size_t)64*KDIM,  d_ + 4096); \
    const unsigned short* sb = Bm + (size_t)(tn*256 + srow)*KDIM + (size_t)(kt_)*32 + scol; \
    GLOAD(sb,                     d_ + 8192); \
    GLOAD(sb + (size_t)64*KDIM,   d_ + 12288); \
    GLOAD(sb + (size_t)128*KDIM,  d_ + 16384); \
    GLOAD(sb + (size_t)192*KDIM,  d_ + 20480); }while(0)
#define RD(OFF) (*(const short8*)(lds + (OFF)))
#define MFMA(a,b,c) __builtin_amdgcn_mfma_f32_16x16x32_bf16(a,b,c,0,0,0)
#define ABAR  asm volatile("s_barrier" ::: "memory")

    f32x4 acc[4][8];
    #pragma unroll
    for (int m=0;m<4;m++)
        #pragma unroll
        for (int n=0;n<8;n++) acc[m][n] = (f32x4){0.f,0.f,0.f,0.f};

    // prologue: tiles 0,1 into slots 0,1; tile0 must be landed (vmcnt(6) keeps tile1 in flight)
    STAGE(0, 0); STAGE(1, 1);
    asm volatile("s_waitcnt vmcnt(6)" ::: "memory");
    ABAR;

    #pragma unroll 3
    for (int kt = 0; kt < NKT2; ++kt) {
        const int sb_ = (kt % 3) * 24576;
        const int tT  = (kt+2 < NKT2) ? kt+2 : NKT2-1;   // tail dummy: slot never read, or
        STAGE(tT, (kt+2) % 3);                            // re-stages identical bytes (benign)
        asm volatile("s_waitcnt vmcnt(12)" ::: "memory"); // retire tile kt; keep kt+1,kt+2

        short8 bfr[8];
        #pragma unroll
        for (int n=0;n<8;n++) bfr[n] = RD(sb_ + bOff + n*1024);
        short8 afr[4];
        #pragma unroll
        for (int m=0;m<4;m++) afr[m] = RD(sb_ + aOff + m*1024);
        #pragma unroll
        for (int m=0;m<4;m++)
            #pragma unroll
            for (int n=0;n<8;n++) acc[m][n] = MFMA(afr[m], bfr[n], acc[m][n]);

        ABAR;   // all waves done with slot kt%3; iter kt+1 may overwrite it
    }
    asm volatile("s_waitcnt vmcnt(0)" ::: "memory");  // drain tail dummies

    const int orow0 = tm*128 + wm*64 + (lane>>4)*4;
    const int ocol0 = tn*256 + wn*128 + lr;
    #pragma unroll
    for (int m=0;m<4;m++){
        #pragma unroll
        for (int n=0;n<8;n++){
            int row = orow0 + m*16, col = ocol0 + n*16;
            #pragma unroll
            for (int j=0;j<4;j++){
                size_t idx = (size_t)(row + j)*N2P + col;
                if (EPI) Cf[idx] = acc[m][n][j] + Dv[col]*bf2f(U16[idx]);
                else     Cb[idx] = f2bf(acc[m][n][j]);
            }
        }
    }
#undef GLOAD
#undef STAGE
#undef RD
#undef MFMA
#undef ABAR
}

// ---------------- scan phase 1: per-(chunk, p) aggregate (Bu in bf16 pairs) -------
__global__ __launch_bounds__(512)
void k_agg(const unsigned int* __restrict__ Bu, const float* __restrict__ lam,
           float* __restrict__ agg)
{
    int p = threadIdx.x, c = blockIdx.x;
    float lrr = lam[2*p], lii = lam[2*p+1];
    float xr = 0.f, xi = 0.f;
    const unsigned int* b2 = Bu + (size_t)c*CHUNK*512 + p;
    #pragma unroll 4
    for (int t=0;t<CHUNK;t++){
        unsigned int b = b2[(size_t)t*512];
        float br = __uint_as_float(b << 16);
        float bi = __uint_as_float(b & 0xffff0000u);
        float tr = lrr*xr - lii*xi + br;
        xi = lrr*xi + lii*xr + bi;
        xr = tr;
    }
    agg[((size_t)c*P_DIM + p)*2]     = xr;
    agg[((size_t)c*P_DIM + p)*2 + 1] = xi;
}

// ---------------- scan phase 2: Kogge-Stone over chunks ---------------------
__global__ __launch_bounds__(256)
void k_scan(const float* __restrict__ agg, const float* __restrict__ lpow,
            float* __restrict__ xinit)
{
    __shared__ float sr[NCHUNK], si[NCHUNK];
    int c = threadIdx.x, p = blockIdx.x;
    float xr = agg[((size_t)c*P_DIM + p)*2];
    float xi = agg[((size_t)c*P_DIM + p)*2 + 1];
    sr[c] = xr; si[c] = xi;
    float wr = lpow[2*p], wi = lpow[2*p+1];
    for (int s=1; s<NCHUNK; s<<=1){
        __syncthreads();
        float ur = 0.f, ui = 0.f;
        if (c >= s){ ur = sr[c-s]; ui = si[c-s]; }
        __syncthreads();
        xr += wr*ur - wi*ui;
        xi += wr*ui + wi*ur;
        sr[c] = xr; si[c] = xi;
        float t = wr*wr - wi*wi; wi = 2.f*wr*wi; wr = t;
    }
    __syncthreads();
    float er = 0.f, ei = 0.f;
    if (c > 0){ er = sr[c-1]; ei = si[c-1]; }
    xinit[((size_t)c*P_DIM + p)*2]     = er;
    xinit[((size_t)c*P_DIM + p)*2 + 1] = ei;
}

// ---------------- scan phase 3: apply + emit bf16 pairs ----------------------
__global__ __launch_bounds__(512)
void k_apply(const unsigned int* __restrict__ Bu, const float* __restrict__ lam,
             const float* __restrict__ xinit, unsigned int* __restrict__ xs)
{
    int p = threadIdx.x, c = blockIdx.x;
    float lrr = lam[2*p], lii = lam[2*p+1];
    float xr = xinit[((size_t)c*P_DIM + p)*2];
    float xi = xinit[((size_t)c*P_DIM + p)*2 + 1];
    const unsigned int* b2 = Bu + (size_t)c*CHUNK*512 + p;
    unsigned int* o = xs + (size_t)c*CHUNK*512 + p;
    #pragma unroll 4
    for (int t=0;t<CHUNK;t++){
        unsigned int b = b2[(size_t)t*512];
        float br = __uint_as_float(b << 16);
        float bi = __uint_as_float(b & 0xffff0000u);
        float tr = lrr*xr - lii*xi + br;
        xi = lrr*xi + lii*xr + bi;
        xr = tr;
        o[(size_t)t*512] = (unsigned int)f2bf(xr) | ((unsigned int)f2bf(xi) << 16);
    }
}

extern "C" void kernel_launch(void* const* d_in, const int* in_sizes, int n_in,
                              void* d_out, int out_size, void* d_ws, size_t ws_size,
                              hipStream_t stream)
{
    const float* u   = (const float*)d_in[0];
    const float* lre = (const float*)d_in[1];
    const float* lim = (const float*)d_in[2];
    const float* B   = (const float*)d_in[3];
    const float* C   = (const float*)d_in[4];
    const float* D   = (const float*)d_in[5];
    const float* ls  = (const float*)d_in[6];
    float* out = (float*)d_out;

    char* w = (char*)d_ws;
    unsigned short* u16  = (unsigned short*)(w + 0);          // 32 MiB
    unsigned short* xs16 = (unsigned short*)(w + 33554432);   // 32 MiB
    unsigned short* Bu16 = (unsigned short*)(w + 67108864);   // 32 MiB
    unsigned short* BB   = (unsigned short*)(w + 100663296);  // 2 MiB
    unsigned short* CC   = (unsigned short*)(w + 102760448);  // 2 MiB
    float* lam   = (float*)(w + 104857600);
    float* coef  = (float*)(w + 104861696);
    float* lpow  = (float*)(w + 104865792);
    float* agg   = (float*)(w + 104869888);                   // 1 MiB
    float* xinit = (float*)(w + 105918464);                   // 1 MiB

    k_prep_lambda<<<1, P_DIM, 0, stream>>>(lre, lim, ls, lam, coef, lpow);
    k_prep_bc<<<4096, 256, 0, stream>>>(B, C, coef, BB, CC);
    k_cast<<<(L_SEQ*H_DIM)/(256*8), 256, 0, stream>>>((const float4*)u, u16);

    gemm128n<0><<<512, 256, 0, stream>>>(u16, BB, nullptr, Bu16, nullptr, nullptr);

    k_agg<<<NCHUNK, P_DIM, 0, stream>>>((const unsigned int*)Bu16, lam, agg);
    k_scan<<<P_DIM, NCHUNK, 0, stream>>>(agg, lpow, xinit);
    k_apply<<<NCHUNK, P_DIM, 0, stream>>>((const unsigned int*)Bu16, lam, xinit,
                                          (unsigned int*)xs16);

    gemm128n<1><<<512, 256, 0, stream>>>(xs16, CC, out, nullptr, D, u16);
}

// Round 11
// 132.712 us; speedup vs baseline: 1.5180x; 1.1295x over previous
//
#include <hip/hip_runtime.h>
#include <math.h>

#define L_SEQ 16384
#define H_DIM 1024
#define P_DIM 512
#define N2P   1024
#define KDIM  1024
#define NKT   16     // KDIM / 64
#define CHUNK 64
#define NCHUNK 256   // L_SEQ / CHUNK

typedef __attribute__((ext_vector_type(8))) short short8;
typedef __attribute__((ext_vector_type(4))) float f32x4;

__device__ __forceinline__ unsigned short f2bf(float f){
    unsigned int u = __float_as_uint(f);
    u = (u + 0x7FFFu + ((u >> 16) & 1u)) >> 16;
    return (unsigned short)u;
}
__device__ __forceinline__ float bf2f(unsigned int lo16){
    return __uint_as_float(lo16 << 16);
}

// ---------------- prep ----------------
__global__ void k_prep_lambda(const float* __restrict__ lre, const float* __restrict__ lim,
                              const float* __restrict__ lstep,
                              float* __restrict__ lam, float* __restrict__ coef,
                              float* __restrict__ lpow)
{
    int p = threadIdx.x;
    double step = exp((double)lstep[p]);
    double dr = (double)lre[p], di = (double)lim[p];
    double ar = dr*step, ai = di*step;
    double er = exp(ar);
    double lbr = er*cos(ai), lbi = er*sin(ai);
    lam[2*p] = (float)lbr; lam[2*p+1] = (float)lbi;
    double nr = lbr - 1.0, ni = lbi;
    double d2 = dr*dr + di*di;
    coef[2*p]   = (float)((nr*dr + ni*di)/d2);
    coef[2*p+1] = (float)((ni*dr - nr*di)/d2);
    double xr = lbr, xi = lbi;
    #pragma unroll
    for (int s=0;s<6;s++){ double t = xr*xr - xi*xi; xi = 2.0*xr*xi; xr = t; } // ^64
    lpow[2*p] = (float)xr; lpow[2*p+1] = (float)xi;
}

__global__ __launch_bounds__(256)
void k_prep_bc(const float* __restrict__ B, const float* __restrict__ C,
               const float* __restrict__ coef,
               unsigned short* __restrict__ BB, unsigned short* __restrict__ CC)
{
    int bid = blockIdx.x;
    if (bid < 2048){
        int i = bid*256 + threadIdx.x;   // i = p*H + h
        int p = i >> 10, h = i & 1023;
        float br = B[2*i], bi = B[2*i+1];
        float cr = coef[2*p], ci = coef[2*p+1];
        BB[(size_t)(2*p)*H_DIM + h]   = f2bf(cr*br - ci*bi);
        BB[(size_t)(2*p+1)*H_DIM + h] = f2bf(cr*bi + ci*br);
    } else {
        int i = (bid-2048)*256 + threadIdx.x;   // i = h*P + p
        int h = i >> 9, p = i & 511;
        float cr = C[2*i], ci = C[2*i+1];
        CC[(size_t)h*N2P + 2*p]     = f2bf(2.f*cr);
        CC[(size_t)h*N2P + 2*p + 1] = f2bf(-2.f*ci);
    }
}

__global__ __launch_bounds__(256)
void k_cast(const float4* __restrict__ u, unsigned short* __restrict__ o)
{
    int i = blockIdx.x*256 + threadIdx.x;
    float4 a = u[2*i], b = u[2*i+1];
    union { short8 v; unsigned short s[8]; } r;
    r.s[0]=f2bf(a.x); r.s[1]=f2bf(a.y); r.s[2]=f2bf(a.z); r.s[3]=f2bf(a.w);
    r.s[4]=f2bf(b.x); r.s[5]=f2bf(b.y); r.s[6]=f2bf(b.z); r.s[7]=f2bf(b.w);
    *reinterpret_cast<short8*>(o + (size_t)i*8) = r.v;
}

// ---------------- GEMM: 128x128, BK=64, 4 waves, 2 co-resident + 2 sequential/CU ----
// C[M][1024] = A[M][1024]bf16 @ Bm[1024][1024]bf16^T
// LDS 64KB: parity p at p*32768: A[128][64]bf16 (16KB) then B[128][64]bf16.
// Per KT (one barrier): vmcnt(8) [kt's stages landed; kt+1's in flight] -> s_barrier
//   -> issue 16 ds_read (ks0 8, ks1 8 interleaved after stages) + 8 gload(kt+1)
//   -> lgkm(8) -> 16 MFMA (ks0) -> lgkm(0) -> 16 MFMA (ks1).
// Counted waits let each wave proceed independently (port serves one wave while
// another MFMAs); 2 independent blocks/CU desync further; grid 1024 = 2 resident
// x 2 sequential so epilogue HBM time overlaps the next block's K-loop.
// Swizzle (both sides, 0 conflicts measured R4-R8): phys 16B-chunk = logical ^ (row&7).
template<int EPI>
__global__ __launch_bounds__(256, 2)
void gemm128(const unsigned short* __restrict__ A, const unsigned short* __restrict__ Bm,
             float* __restrict__ Cf, unsigned short* __restrict__ Cb,
             const float* __restrict__ Dv, const unsigned short* __restrict__ U16)
{
    __shared__ char lds[65536];
    const int tid  = threadIdx.x;
    const int lane = tid & 63;
    const int wid  = tid >> 6;
    const int wm = wid >> 1, wn = wid & 1;            // 2(M) x 2(N), wave = 64x64
    const int wg = ((int)blockIdx.x & 7) * 128 + ((int)blockIdx.x >> 3);  // XCD swizzle
    const int tm = wg >> 3, tn = wg & 7;
    const int lr = lane & 15;

    // staging: thread covers row (g*32 + tid>>3), 16B chunk tid&7; dst linear tid*16;
    // source col pre-swizzled: logical chunk = (tid&7)^(row&7)
    const int srow = tid >> 3;                               // 0..31
    const int scol = ((tid & 7) ^ ((tid >> 3) & 7)) << 3;    // ushort units
    // reads: row R = (wm|wn)*64 + m*16 + lr; byte = R*128 + ((g|4ks)^(R&7))*16
    const int kc0 = (((lane >> 4)      ^ (lr & 7)) << 4);
    const int kc1 = ((((lane >> 4) | 4) ^ (lr & 7)) << 4);
    const int aOff = (wm*64 + lr)*128;                       // + m*2048 + kc
    const int bOff = 16384 + (wn*64 + lr)*128;               // + n*2048 + kc

#define GLOAD(SRC, DST) __builtin_amdgcn_global_load_lds( \
        (const __attribute__((address_space(1))) void*)(SRC), \
        (__attribute__((address_space(3))) void*)(DST), 16, 0, 0)
#define STAGE(kt_) do{ \
    char* d_ = lds + (((kt_)&1)<<15) + tid*16; \
    const unsigned short* sa = A + (size_t)(tm*128 + srow)*KDIM + (size_t)(kt_)*64 + scol; \
    GLOAD(sa,                    d_); \
    GLOAD(sa + (size_t)32*KDIM,  d_ + 4096); \
    GLOAD(sa + (size_t)64*KDIM,  d_ + 8192); \
    GLOAD(sa + (size_t)96*KDIM,  d_ + 12288); \
    const unsigned short* sb = Bm + (size_t)(tn*128 + srow)*KDIM + (size_t)(kt_)*64 + scol; \
    GLOAD(sb,                    d_ + 16384); \
    GLOAD(sb + (size_t)32*KDIM,  d_ + 20480); \
    GLOAD(sb + (size_t)64*KDIM,  d_ + 24576); \
    GLOAD(sb + (size_t)96*KDIM,  d_ + 28672); }while(0)
#define RD(OFF) (*(const short8*)(lds + (OFF)))
#define MFMA(a,b,c) __builtin_amdgcn_mfma_f32_16x16x32_bf16(a,b,c,0,0,0)
#define LGKM(N) do{ asm volatile("s_waitcnt lgkmcnt(" #N ")" ::: "memory"); \
                    __builtin_amdgcn_sched_barrier(0); }while(0)
#define ABAR  asm volatile("s_barrier" ::: "memory")

    f32x4 acc[4][4];
    #pragma unroll
    for (int m=0;m<4;m++)
        #pragma unroll
        for (int n=0;n<4;n++) acc[m][n] = (f32x4){0.f,0.f,0.f,0.f};

    // prologue: stage KT0 (parity 0) and KT1 (parity 1); KT0 must land before reads
    STAGE(0); STAGE(1);

    for (int kt = 0; kt < NKT; ++kt) {
        const int sb = (kt & 1) << 15;
        const int tN = (kt+2 < NKT) ? kt+2 : NKT-2+((kt+2)&1); // tail dummy, same parity, never-read slot content benign
        asm volatile("s_waitcnt vmcnt(8)" ::: "memory");  // kt's 8 stages landed; kt+1's 8 in flight
        ABAR;                                             // all waves ready; prev reads of this parity long retired
        // ks0 reads
        short8 a0[4], b0[4], a1v[4], b1v[4];
        #pragma unroll
        for (int m=0;m<4;m++) a0[m] = RD(sb + aOff + m*2048 + kc0);
        #pragma unroll
        for (int n=0;n<4;n++) b0[n] = RD(sb + bOff + n*2048 + kc0);
        STAGE(tN);                                        // 8 gloads for kt+2 (parity kt&1... = (kt+2)&1 ✓)
        // ks1 reads stream under ks0 MFMA
        #pragma unroll
        for (int m=0;m<4;m++) a1v[m] = RD(sb + aOff + m*2048 + kc1);
        #pragma unroll
        for (int n=0;n<4;n++) b1v[n] = RD(sb + bOff + n*2048 + kc1);
        LGKM(8);   // ks0's 8 done; ks1's 8 outstanding
        #pragma unroll
        for (int m=0;m<4;m++)
            #pragma unroll
            for (int n=0;n<4;n++) acc[m][n] = MFMA(a0[m], b0[n], acc[m][n]);
        LGKM(0);   // ks1 done
        #pragma unroll
        for (int m=0;m<4;m++)
            #pragma unroll
            for (int n=0;n<4;n++) acc[m][n] = MFMA(a1v[m], b1v[n], acc[m][n]);
    }
    asm volatile("s_waitcnt vmcnt(0)" ::: "memory");  // drain tail dummies

    const int orow0 = tm*128 + wm*64 + (lane>>4)*4;
    const int ocol0 = tn*128 + wn*64 + lr;
    #pragma unroll
    for (int m=0;m<4;m++){
        #pragma unroll
        for (int n=0;n<4;n++){
            int row = orow0 + m*16, col = ocol0 + n*16;
            #pragma unroll
            for (int j=0;j<4;j++){
                size_t idx = (size_t)(row + j)*N2P + col;
                if (EPI) Cf[idx] = acc[m][n][j] + Dv[col]*bf2f(U16[idx]);
                else     Cb[idx] = f2bf(acc[m][n][j]);
            }
        }
    }
#undef GLOAD
#undef STAGE
#undef RD
#undef MFMA
#undef LGKM
#undef ABAR
}

// ---------------- scan phase 1: per-(chunk, p) aggregate (Bu in bf16 pairs) -------
__global__ __launch_bounds__(512)
void k_agg(const unsigned int* __restrict__ Bu, const float* __restrict__ lam,
           float* __restrict__ agg)
{
    int p = threadIdx.x, c = blockIdx.x;
    float lrr = lam[2*p], lii = lam[2*p+1];
    float xr = 0.f, xi = 0.f;
    const unsigned int* b2 = Bu + (size_t)c*CHUNK*512 + p;
    #pragma unroll 4
    for (int t=0;t<CHUNK;t++){
        unsigned int b = b2[(size_t)t*512];
        float br = __uint_as_float(b << 16);
        float bi = __uint_as_float(b & 0xffff0000u);
        float tr = lrr*xr - lii*xi + br;
        xi = lrr*xi + lii*xr + bi;
        xr = tr;
    }
    agg[((size_t)c*P_DIM + p)*2]     = xr;
    agg[((size_t)c*P_DIM + p)*2 + 1] = xi;
}

// ---------------- scan phase 2: Kogge-Stone over chunks ---------------------
__global__ __launch_bounds__(256)
void k_scan(const float* __restrict__ agg, const float* __restrict__ lpow,
            float* __restrict__ xinit)
{
    __shared__ float sr[NCHUNK], si[NCHUNK];
    int c = threadIdx.x, p = blockIdx.x;
    float xr = agg[((size_t)c*P_DIM + p)*2];
    float xi = agg[((size_t)c*P_DIM + p)*2 + 1];
    sr[c] = xr; si[c] = xi;
    float wr = lpow[2*p], wi = lpow[2*p+1];
    for (int s=1; s<NCHUNK; s<<=1){
        __syncthreads();
        float ur = 0.f, ui = 0.f;
        if (c >= s){ ur = sr[c-s]; ui = si[c-s]; }
        __syncthreads();
        xr += wr*ur - wi*ui;
        xi += wr*ui + wi*ur;
        sr[c] = xr; si[c] = xi;
        float t = wr*wr - wi*wi; wi = 2.f*wr*wi; wr = t;
    }
    __syncthreads();
    float er = 0.f, ei = 0.f;
    if (c > 0){ er = sr[c-1]; ei = si[c-1]; }
    xinit[((size_t)c*P_DIM + p)*2]     = er;
    xinit[((size_t)c*P_DIM + p)*2 + 1] = ei;
}

// ---------------- scan phase 3: apply + emit bf16 pairs ----------------------
__global__ __launch_bounds__(512)
void k_apply(const unsigned int* __restrict__ Bu, const float* __restrict__ lam,
             const float* __restrict__ xinit, unsigned int* __restrict__ xs)
{
    int p = threadIdx.x, c = blockIdx.x;
    float lrr = lam[2*p], lii = lam[2*p+1];
    float xr = xinit[((size_t)c*P_DIM + p)*2];
    float xi = xinit[((size_t)c*P_DIM + p)*2 + 1];
    const unsigned int* b2 = Bu + (size_t)c*CHUNK*512 + p;
    unsigned int* o = xs + (size_t)c*CHUNK*512 + p;
    #pragma unroll 4
    for (int t=0;t<CHUNK;t++){
        unsigned int b = b2[(size_t)t*512];
        float br = __uint_as_float(b << 16);
        float bi = __uint_as_float(b & 0xffff0000u);
        float tr = lrr*xr - lii*xi + br;
        xi = lrr*xi + lii*xr + bi;
        xr = tr;
        o[(size_t)t*512] = (unsigned int)f2bf(xr) | ((unsigned int)f2bf(xi) << 16);
    }
}

extern "C" void kernel_launch(void* const* d_in, const int* in_sizes, int n_in,
                              void* d_out, int out_size, void* d_ws, size_t ws_size,
                              hipStream_t stream)
{
    const float* u   = (const float*)d_in[0];
    const float* lre = (const float*)d_in[1];
    const float* lim = (const float*)d_in[2];
    const float* B   = (const float*)d_in[3];
    const float* C   = (const float*)d_in[4];
    const float* D   = (const float*)d_in[5];
    const float* ls  = (const float*)d_in[6];
    float* out = (float*)d_out;

    char* w = (char*)d_ws;
    unsigned short* u16  = (unsigned short*)(w + 0);          // 32 MiB
    unsigned short* xs16 = (unsigned short*)(w + 33554432);   // 32 MiB
    unsigned short* Bu16 = (unsigned short*)(w + 67108864);   // 32 MiB
    unsigned short* BB   = (unsigned short*)(w + 100663296);  // 2 MiB
    unsigned short* CC   = (unsigned short*)(w + 102760448);  // 2 MiB
    float* lam   = (float*)(w + 104857600);
    float* coef  = (float*)(w + 104861696);
    float* lpow  = (float*)(w + 104865792);
    float* agg   = (float*)(w + 104869888);                   // 1 MiB
    float* xinit = (float*)(w + 105918464);                   // 1 MiB

    k_prep_lambda<<<1, P_DIM, 0, stream>>>(lre, lim, ls, lam, coef, lpow);
    k_prep_bc<<<4096, 256, 0, stream>>>(B, C, coef, BB, CC);
    k_cast<<<(L_SEQ*H_DIM)/(256*8), 256, 0, stream>>>((const float4*)u, u16);

    gemm128<0><<<1024, 256, 0, stream>>>(u16, BB, nullptr, Bu16, nullptr, nullptr);

    k_agg<<<NCHUNK, P_DIM, 0, stream>>>((const unsigned int*)Bu16, lam, agg);
    k_scan<<<P_DIM, NCHUNK, 0, stream>>>(agg, lpow, xinit);
    k_apply<<<NCHUNK, P_DIM, 0, stream>>>((const unsigned int*)Bu16, lam, xinit,
                                          (unsigned int*)xs16);

    gemm128<1><<<1024, 256, 0, stream>>>(xs16, CC, out, nullptr, D, u16);
}